// Round 8
// baseline (79.880 us; speedup 1.0000x reference)
//
#include <hip/hip_runtime.h>

#define F_BINS  257
#define T_STEPS 65536
#define N_ACT   256
#define NBLK    4096          // k_gemm blocks, 16 t-columns each
#define XO_CHUNK 1028         // float4 per block: 257*65536/4/4096, exact

typedef float f32x4 __attribute__((ext_vector_type(4)));
typedef short s16x8 __attribute__((ext_vector_type(8)));
typedef unsigned u32x4 __attribute__((ext_vector_type(4)));
typedef unsigned long long u64;

// ws layout:
//   [0]       double Sc
//   [64]      unsigned mask[8]
//   [1024]    u64 argkey[65536]          (memset 0 = -inf keys)
//   [525312]  double partial[4096]       (per-block xo^2 sums; fully written)
//   [558080]  uchar Gfrag[147456]        (B frags: [kk][ng][lane][16B])
#define WS_SC    0
#define WS_MASK  64
#define WS_KEY   1024
#define WS_PART  525312
#define WS_GFRAG 558080

__device__ __forceinline__ unsigned short f2bf_rne(float x) {
  unsigned u = __builtin_bit_cast(unsigned, x);
  return (unsigned short)((u + 0x7FFFu + ((u >> 16) & 1u)) >> 16);
}
// bf16(hi)<<16 | bf16(lo) by truncation: one v_perm_b32
__device__ __forceinline__ unsigned pack_bf(float hi, float lo) {
  return __builtin_amdgcn_perm(__builtin_bit_cast(unsigned, hi),
                               __builtin_bit_cast(unsigned, lo), 0x07060302u);
}
#define PACK8(v) __builtin_bit_cast(s16x8, (u32x4){                          \
      pack_bf((v)[1], (v)[0]), pack_bf((v)[3], (v)[2]),                      \
      pack_bf((v)[5], (v)[4]), pack_bf((v)[7], (v)[6])})
// monotonic float->u32 (order-preserving, finite inputs)
__device__ __forceinline__ unsigned mono(float v) {
  unsigned u = __builtin_bit_cast(unsigned, v);
  return u ^ (unsigned)(((int)u >> 31) | (int)0x80000000);
}

// ---------------------------------------------------------------------------
// B fragments in MFMA order:
// Gfrag[((kk*16+ng)*64+lane)*16] = 8 bf16 of G[f=32kk+8(lane>>4)+j][a=16ng+(lane&15)]
// ---------------------------------------------------------------------------
__global__ __launch_bounds__(256) void k_prep(const float* __restrict__ G,
                                              unsigned char* __restrict__ gfrag) {
  const int u = blockIdx.x * 256 + threadIdx.x;   // 0..9215
  const int lane = u & 63, ng = (u >> 6) & 15, kk = u >> 10;
  const int r16 = lane & 15, g = lane >> 4;
  const int a = ng * 16 + r16;
  unsigned short h[8];
#pragma unroll
  for (int j = 0; j < 8; ++j) {
    const int f = kk * 32 + 8 * g + j;
    h[j] = (f < F_BINS) ? f2bf_rne(G[f * N_ACT + a]) : (unsigned short)0;
  }
  u32x4 w;
#pragma unroll
  for (int i = 0; i < 4; ++i)
    w[i] = (unsigned)h[2 * i] | ((unsigned)h[2 * i + 1] << 16);
  *(u32x4*)(gfrag + (size_t)u * 16) = w;
}

// ---------------------------------------------------------------------------
// High-occupancy GEMM+argmax+xo^2. Block = 16 t-columns; each wave computes
// the same 16 t against its own 64-action quarter (quarters merged via u64
// atomicMax keys). No LDS tiles, no barriers; A depth-3 + B depth-2 rolling
// register prefetch, sched_barrier(0) per kk bounds liveness (~100 VGPR).
// ---------------------------------------------------------------------------
__global__ __launch_bounds__(256, 4) void k_gemm(
    const float* __restrict__ xs, const float* __restrict__ xo,
    const unsigned char* __restrict__ gfrag,
    u64* __restrict__ argkey, double* __restrict__ partial) {
  const int tid = threadIdx.x, lane = tid & 63, wv = tid >> 6;
  const int g = lane >> 4, r16 = lane & 15;
  const int t0 = blockIdx.x * 16;
  const int trow = t0 + r16;

  // A: 8 dwords (f-run 8g..8g+7 at fixed t) into slot s
#define LOAD_A(s, kkv)                                                        \
  {                                                                           \
    _Pragma("unroll") for (int j = 0; j < 8; ++j) {                           \
      int f = 32 * (kkv) + 8 * g + j;                                         \
      if ((kkv) == 8) f = f > 256 ? 256 : f; /* Gfrag zero rows cover pad */  \
      va[s][j] = xs[(size_t)f * T_STEPS + trow];                              \
    }                                                                         \
  }
  // B: this wave's 4 action-tiles for slice kk (4 x 16B, L2-resident)
#define LOAD_B(s, kkv)                                                        \
  {                                                                           \
    _Pragma("unroll") for (int n = 0; n < 4; ++n)                             \
      bq[s][n] = *(const s16x8*)(gfrag +                                      \
          (size_t)((((kkv) * 16 + 4 * wv + n) * 64 + lane) * 16));            \
  }

  float va[3][8];
  s16x8 bq[2][4];
  LOAD_A(0, 0) LOAD_A(1, 1) LOAD_A(2, 2)
  LOAD_B(0, 0) LOAD_B(1, 1)

  f32x4 acc[4];
#pragma unroll
  for (int n = 0; n < 4; ++n) acc[n] = (f32x4){0.f, 0.f, 0.f, 0.f};

#pragma unroll
  for (int kk = 0; kk < 9; ++kk) {
    const int as = kk % 3, bs = kk % 2;
    const s16x8 af = PACK8(va[as]);
#pragma unroll
    for (int n = 0; n < 4; ++n)
      acc[n] = __builtin_amdgcn_mfma_f32_16x16x32_bf16(af, bq[bs][n], acc[n], 0, 0, 0);
    if (kk + 3 <= 8) LOAD_A(as, kk + 3)
    if (kk + 2 <= 8) LOAD_B(bs, kk + 2)
    __builtin_amdgcn_sched_barrier(0);  // bound liveness: no cross-kk hoisting
  }
#undef LOAD_A
#undef LOAD_B

  // ---- argmax: lane(g,r16) holds rows t=4g+q, cols a=64wv+16n+r16 ----
#pragma unroll
  for (int q = 0; q < 4; ++q) {
    float bv = acc[0][q];
    int   bc = 64 * wv + r16;
#pragma unroll
    for (int n = 1; n < 4; ++n) {
      const int c = 64 * wv + 16 * n + r16;
      if (acc[n][q] > bv) { bv = acc[n][q]; bc = c; }
    }
    u64 key = ((u64)mono(bv) << 32) | (unsigned)(~bc);
#pragma unroll
    for (int m = 1; m <= 8; m <<= 1) {
      const u64 ok = __shfl_xor(key, m, 64);
      if (ok > key) key = ok;
    }
    if (r16 == 0) atomicMax(&argkey[t0 + 4 * g + q], key);
  }

  // ---- xo^2 over this block's contiguous 1028-float4 chunk ----
  const float4* xo4 = (const float4*)xo;
  const size_t base = (size_t)blockIdx.x * XO_CHUNK;
  const float4 w0 = xo4[base + tid];
  const float4 w1 = xo4[base + tid + 256];
  const float4 w2 = xo4[base + tid + 512];
  const float4 w3 = xo4[base + tid + 768];
  double ds = ((double)fmaf(w0.x, w0.x, w0.y * w0.y) +
               (double)fmaf(w0.z, w0.z, w0.w * w0.w)) +
              ((double)fmaf(w1.x, w1.x, w1.y * w1.y) +
               (double)fmaf(w1.z, w1.z, w1.w * w1.w)) +
              ((double)fmaf(w2.x, w2.x, w2.y * w2.y) +
               (double)fmaf(w2.z, w2.z, w2.w * w2.w)) +
              ((double)fmaf(w3.x, w3.x, w3.y * w3.y) +
               (double)fmaf(w3.z, w3.z, w3.w * w3.w));
  if (tid < XO_CHUNK - 1024) {
    const float4 w4 = xo4[base + tid + 1024];
    ds += (double)fmaf(w4.x, w4.x, w4.y * w4.y) +
          (double)fmaf(w4.z, w4.z, w4.w * w4.w);
  }
#pragma unroll
  for (int off = 32; off; off >>= 1) ds += __shfl_down(ds, off);
  __shared__ double sd[4];
  if (lane == 0) sd[wv] = ds;
  __syncthreads();
  if (tid == 0) partial[blockIdx.x] = sd[0] + sd[1] + sd[2] + sd[3];
}

// ---------------------------------------------------------------------------
__global__ __launch_bounds__(256) void k_mask(const u64* __restrict__ argkey,
                                              unsigned* __restrict__ mask) {
  __shared__ unsigned lm[8];
  const int tid = threadIdx.x;
  if (tid < 8) lm[tid] = 0u;
  __syncthreads();
  const int t = blockIdx.x * 256 + tid;
  const unsigned bc = ~(unsigned)(argkey[t] & 0xFFFFFFFFull);
  atomicOr(&lm[(bc >> 5) & 7], 1u << (bc & 31));
  __syncthreads();
  if (tid < 8 && lm[tid]) atomicOr(&mask[tid], lm[tid]);
}

// ---------------------------------------------------------------------------
// Correction for selected columns t = a < 256:
//   Sc += sum_f (G*xs)^2 - 2*(G*xs)*xo
// ---------------------------------------------------------------------------
__global__ __launch_bounds__(256) void k_corr(
    const float* __restrict__ xs, const float* __restrict__ xo,
    const float* __restrict__ G, const unsigned* __restrict__ mask,
    double* __restrict__ Sc) {
  const int f = blockIdx.x, a = threadIdx.x;
  const bool sel = (mask[a >> 5] >> (a & 31)) & 1u;
  const float gv  = G[f * N_ACT + a];
  const float xsv = xs[(size_t)f * T_STEPS + a];
  const float xov = xo[(size_t)f * T_STEPS + a];
  const float gx  = gv * xsv;
  double acc = sel ? (double)(gx * (gx - 2.f * xov)) : 0.0;
#pragma unroll
  for (int off = 32; off; off >>= 1) acc += __shfl_down(acc, off);
  __shared__ double sdc[4];
  if ((threadIdx.x & 63) == 0) sdc[threadIdx.x >> 6] = acc;
  __syncthreads();
  if (threadIdx.x == 0) atomicAdd(Sc, sdc[0] + sdc[1] + sdc[2] + sdc[3]);
}

__global__ __launch_bounds__(256) void k_final(const double* __restrict__ partial,
                                               const double* __restrict__ Sc,
                                               float* __restrict__ out) {
  const int tid = threadIdx.x;
  double s = 0.0;
#pragma unroll
  for (int i = 0; i < 16; ++i) s += partial[tid + 256 * i];
#pragma unroll
  for (int off = 32; off; off >>= 1) s += __shfl_down(s, off);
  __shared__ double sd[4];
  if ((tid & 63) == 0) sd[tid >> 6] = s;
  __syncthreads();
  if (tid == 0)
    out[0] = (float)((sd[0] + sd[1] + sd[2] + sd[3] + Sc[0]) /
                     ((double)F_BINS * (double)T_STEPS));
}

extern "C" void kernel_launch(void* const* d_in, const int* in_sizes, int n_in,
                              void* d_out, int out_size, void* d_ws, size_t ws_size,
                              hipStream_t stream) {
  const float* x_out    = (const float*)d_in[0];
  const float* x_source = (const float*)d_in[1];
  // d_in[2] (x_clean) is dead: argmin_a(clean_sum - proj) == argmax_a proj
  const float* G        = (const float*)d_in[3];

  char* ws = (char*)d_ws;
  double*        Sc      = (double*)(ws + WS_SC);
  unsigned*      mask    = (unsigned*)(ws + WS_MASK);
  u64*           argkey  = (u64*)(ws + WS_KEY);
  double*        partial = (double*)(ws + WS_PART);
  unsigned char* gfrag   = (unsigned char*)(ws + WS_GFRAG);

  hipMemsetAsync(d_ws, 0, WS_PART, stream);  // Sc, mask, argkey
  k_prep <<<36, 256, 0, stream>>>(G, gfrag);
  k_gemm <<<NBLK, 256, 0, stream>>>(x_source, x_out, gfrag, argkey, partial);
  k_mask <<<T_STEPS / 256, 256, 0, stream>>>(argkey, mask);
  k_corr <<<F_BINS, 256, 0, stream>>>(x_source, x_out, G, mask, Sc);
  k_final<<<1, 256, 0, stream>>>(partial, Sc, (float*)d_out);
}

// Round 9
// 53.260 us; speedup vs baseline: 1.4998x; 1.4998x over previous
//
#include <hip/hip_runtime.h>

#define F_BINS  257
#define T_STEPS 65536
#define N_ACT   256
#define TM      128           // t-columns per block (full 512B xs lines)
#define NBLK    512           // T_STEPS / TM
#define XO_CHUNK 8224         // float4 per block: 257*65536/4/512, exact

typedef float f32x4 __attribute__((ext_vector_type(4)));
typedef short s16x8 __attribute__((ext_vector_type(8)));
typedef unsigned u32x4 __attribute__((ext_vector_type(4)));

// ws layout:
//   [0]      double Sc
//   [8]      double Sb
//   [16384]  unsigned maskp[NBLK*8]
//   [65536]  uchar Gfrag[147456]   (B frags, MFMA order: [kk][n][lane][16B])
#define WS_SC    0
#define WS_SB    8
#define WS_MASK  16384
#define WS_GFRAG 65536

__device__ __forceinline__ unsigned short f2bf_rne(float x) {
  unsigned u = __builtin_bit_cast(unsigned, x);
  return (unsigned short)((u + 0x7FFFu + ((u >> 16) & 1u)) >> 16);
}
// bf16(hi)<<16 | bf16(lo) by truncation: one v_perm_b32
__device__ __forceinline__ unsigned pack_bf(float hi, float lo) {
  return __builtin_amdgcn_perm(__builtin_bit_cast(unsigned, hi),
                               __builtin_bit_cast(unsigned, lo), 0x07060302u);
}
#define PACK8(v) __builtin_bit_cast(s16x8, (u32x4){                          \
      pack_bf((v)[1], (v)[0]), pack_bf((v)[3], (v)[2]),                      \
      pack_bf((v)[5], (v)[4]), pack_bf((v)[7], (v)[6])})

// ---------------------------------------------------------------------------
// B fragments in MFMA order:
// Gfrag[((kk*16+n)*64+lane)*16] = 8 bf16 of G[f=32kk+8(lane>>4)+j][a=16n+(lane&15)]
// ---------------------------------------------------------------------------
__global__ __launch_bounds__(256) void k_prep(const float* __restrict__ G,
                                              unsigned char* __restrict__ gfrag) {
  const int u = blockIdx.x * 256 + threadIdx.x;   // 0..9215
  const int lane = u & 63, ng = (u >> 6) & 15, kk = u >> 10;
  const int r16 = lane & 15, g = lane >> 4;
  const int a = ng * 16 + r16;
  unsigned short h[8];
#pragma unroll
  for (int j = 0; j < 8; ++j) {
    const int f = kk * 32 + 8 * g + j;
    h[j] = (f < F_BINS) ? f2bf_rne(G[f * N_ACT + a]) : (unsigned short)0;
  }
  u32x4 w;
#pragma unroll
  for (int i = 0; i < 4; ++i)
    w[i] = (unsigned)h[2 * i] | ((unsigned)h[2 * i + 1] << 16);
  *(u32x4*)(gfrag + (size_t)u * 16) = w;
}

// ---------------------------------------------------------------------------
// GEMM+argmax+xo^2. Block = 128 t; wave wv owns t in [t0+32wv, +32) (2 tiles)
// x all 256 actions. B: 16KB kk-slices -> LDS ring-3 (global_load_lds, stage
// distance 2). A: direct per-wave loads, 2 reg slots. Loop sync = pack's
// implicit counted vmcnt (own stage retired by in-order rule) + 1 s_barrier.
// ---------------------------------------------------------------------------
__global__ __launch_bounds__(256, 2) void k_gemm(
    const float* __restrict__ xs, const float* __restrict__ xo,
    const unsigned char* __restrict__ gfrag,
    unsigned* __restrict__ maskp, double* __restrict__ Sb) {
  const int tid = threadIdx.x, lane = tid & 63, wv = tid >> 6;
  const int g = lane >> 4, r16 = lane & 15;
  const int t0 = blockIdx.x * TM;
  const int trow = t0 + 32 * wv + r16;   // tau=0 row; tau=1 is +16

  __shared__ __align__(16) unsigned char Bb[3][16384];
  __shared__ unsigned lmask[8];
  __shared__ double sd[4];
  if (tid < 8) lmask[tid] = 0u;

  // stage one 16KB B kk-slice: wave wv does n = 4wv..4wv+3 (1KB each)
#define STAGE_B(buf, kkv)                                                     \
  {                                                                           \
    _Pragma("unroll") for (int i = 0; i < 4; ++i) {                           \
      const unsigned char* src = gfrag +                                      \
          (size_t)((((kkv) * 16 + 4 * wv + i) * 64 + lane) * 16);             \
      unsigned char* dst = &Bb[(buf)][(4 * wv + i) * 1024];                   \
      __builtin_amdgcn_global_load_lds(                                       \
          (const __attribute__((address_space(1))) unsigned*)src,             \
          (__attribute__((address_space(3))) unsigned*)dst, 16, 0, 0);        \
    }                                                                         \
  }
  // A: 16 dwords into slot s; wave covers one full 128B line per f
#define LOAD_A(s, kkv)                                                        \
  {                                                                           \
    _Pragma("unroll") for (int tau = 0; tau < 2; ++tau)                       \
    _Pragma("unroll") for (int j = 0; j < 8; ++j) {                           \
      int f = 32 * (kkv) + 8 * g + j;                                         \
      if ((kkv) == 8) f = f > 256 ? 256 : f; /* Gfrag zero rows cover pad */  \
      va[s][tau][j] = xs[(size_t)f * T_STEPS + trow + 16 * tau];              \
    }                                                                         \
  }

  float va[2][2][8];
  STAGE_B(0, 0)
  LOAD_A(0, 0)
  STAGE_B(1, 1)
  LOAD_A(1, 1)

  f32x4 acc[2][16];
#pragma unroll
  for (int tau = 0; tau < 2; ++tau)
#pragma unroll
    for (int n = 0; n < 16; ++n) acc[tau][n] = (f32x4){0.f, 0.f, 0.f, 0.f};

#pragma unroll
  for (int kk = 0; kk < 9; ++kk) {
    const int s = kk & 1;
    // compiler waits vmcnt(20) for va[s] here; in-order retirement then
    // guarantees this wave's own STAGE_B(kk) (issued before LOAD_A(kk)) done.
    const s16x8 af0 = PACK8(va[s][0]);
    const s16x8 af1 = PACK8(va[s][1]);
    __builtin_amdgcn_s_barrier();      // => ALL waves' slice-kk stages done;
                                       //    all slice-(kk-1) reads consumed
    if (kk + 2 <= 8) {
      STAGE_B((kk + 2) % 3, kk + 2)    // overwrites slice kk-1: safe now
      LOAD_A(s, kk + 2)
      __builtin_amdgcn_sched_barrier(0);  // pin prefetch issue before MFMAs
    }
    const unsigned char* bp = &Bb[kk % 3][lane * 16];
#pragma unroll
    for (int n = 0; n < 16; ++n) {
      const s16x8 bfr = *(const s16x8*)(bp + n * 1024);
      acc[0][n] = __builtin_amdgcn_mfma_f32_16x16x32_bf16(af0, bfr, acc[0][n], 0, 0, 0);
      acc[1][n] = __builtin_amdgcn_mfma_f32_16x16x32_bf16(af1, bfr, acc[1][n], 0, 0, 0);
    }
  }
#undef STAGE_B
#undef LOAD_A

  // ---- argmax per row; D layout: row=4g+q, col=16n+r16 ----
  // t = t0 + 32wv + 16tau + 4g + q; reduce over n in-lane, then over r16.
#pragma unroll
  for (int tau = 0; tau < 2; ++tau) {
#pragma unroll
    for (int q = 0; q < 4; ++q) {
      float bv = acc[tau][0][q];
      int   bc = r16;
#pragma unroll
      for (int n = 1; n < 16; ++n) {
        const int c = 16 * n + r16;
        if (acc[tau][n][q] > bv) { bv = acc[tau][n][q]; bc = c; }
      }
#pragma unroll
      for (int m = 1; m <= 8; m <<= 1) {
        const float ov = __shfl_xor(bv, m);
        const int   oc = __shfl_xor(bc, m);
        if (ov > bv || (ov == bv && oc < bc)) { bv = ov; bc = oc; }
      }
      if (r16 == 0) atomicOr(&lmask[bc >> 5], 1u << (bc & 31));
    }
  }
  __syncthreads();
  if (tid < 8) maskp[blockIdx.x * 8 + tid] = lmask[tid];

  // ---- fused sum of x_out^2: contiguous per-block float4 chunk ----
  const float4* xo4 = (const float4*)xo;
  const size_t base = (size_t)blockIdx.x * XO_CHUNK;
  double ds = 0.0;
#pragma unroll 8
  for (int i = tid; i < XO_CHUNK; i += 256) {
    const float4 v = xo4[base + i];
    ds += (double)fmaf(v.x, v.x, v.y * v.y) + (double)fmaf(v.z, v.z, v.w * v.w);
  }
#pragma unroll
  for (int off = 32; off; off >>= 1) ds += __shfl_down(ds, off);
  if (lane == 0) sd[wv] = ds;
  __syncthreads();
  if (tid == 0) atomicAdd(Sb, sd[0] + sd[1] + sd[2] + sd[3]);
}

// ---------------------------------------------------------------------------
// OR-reduce per-block masks, then correction for selected columns t = a:
//   Sc += sum_f (G*xs)^2 - 2*(G*xs)*xo
// ---------------------------------------------------------------------------
__global__ __launch_bounds__(256) void k_corr(
    const float* __restrict__ xs, const float* __restrict__ xo,
    const float* __restrict__ G, const unsigned* __restrict__ maskp,
    double* __restrict__ Sc) {
  __shared__ unsigned m8[8];
  const int tid = threadIdx.x;
  if (tid < 8) m8[tid] = 0u;
  __syncthreads();
  unsigned m = 0;
  for (int b = tid >> 3; b < NBLK; b += 32) m |= maskp[b * 8 + (tid & 7)];
  atomicOr(&m8[tid & 7], m);
  __syncthreads();
  const int f = blockIdx.x, a = tid;
  const bool sel = (m8[a >> 5] >> (a & 31)) & 1u;
  const float gv  = G[f * N_ACT + a];
  const float xsv = xs[(size_t)f * T_STEPS + a];
  const float xov = xo[(size_t)f * T_STEPS + a];
  const float gx  = gv * xsv;
  double acc = sel ? (double)(gx * (gx - 2.f * xov)) : 0.0;
#pragma unroll
  for (int off = 32; off; off >>= 1) acc += __shfl_down(acc, off);
  __shared__ double sdc[4];
  if ((tid & 63) == 0) sdc[tid >> 6] = acc;
  __syncthreads();
  if (tid == 0) atomicAdd(Sc, sdc[0] + sdc[1] + sdc[2] + sdc[3]);
}

__global__ void k_final(const double* __restrict__ Sb,
                        const double* __restrict__ Sc,
                        float* __restrict__ out) {
  out[0] = (float)((Sb[0] + Sc[0]) / ((double)F_BINS * (double)T_STEPS));
}

extern "C" void kernel_launch(void* const* d_in, const int* in_sizes, int n_in,
                              void* d_out, int out_size, void* d_ws, size_t ws_size,
                              hipStream_t stream) {
  const float* x_out    = (const float*)d_in[0];
  const float* x_source = (const float*)d_in[1];
  // d_in[2] (x_clean) is dead: argmin_a(clean_sum - proj) == argmax_a proj
  const float* G        = (const float*)d_in[3];

  char* ws = (char*)d_ws;
  double*        Sc    = (double*)(ws + WS_SC);
  double*        Sb    = (double*)(ws + WS_SB);
  unsigned*      maskp = (unsigned*)(ws + WS_MASK);
  unsigned char* gfrag = (unsigned char*)(ws + WS_GFRAG);

  hipMemsetAsync(d_ws, 0, 64, stream);   // Sc, Sb
  k_prep <<<36, 256, 0, stream>>>(G, gfrag);
  k_gemm <<<NBLK, 256, 0, stream>>>(x_source, x_out, gfrag, maskp, Sb);
  k_corr <<<F_BINS, 256, 0, stream>>>(x_source, x_out, G, maskp, Sc);
  k_final<<<1, 1, 0, stream>>>(Sb, Sc, (float*)d_out);
}